// Round 5
// baseline (688.696 us; speedup 1.0000x reference)
//
#include <hip/hip_runtime.h>

// ImprovedGraphSAGE: 4x SAGEConv(aggr='lstm') on MI355X.
// N=20000 nodes, DEG=16, F_IN=HID=128, OUT=64, E=320000.
//
// R5 structure (occupancy fix: kill 64KB LDS staging):
//   0) prep_weights: Wih,Whh -> bf16; bsum = bih+bhh     (once)
//   1) cast_bf     : xbf = bf16(x)                       (layer 0 only)
//   2) lstm_fused  : x gathered per-step DIRECTLY into MFMA A-fragments
//                    (4x16B loads, depth-1 prefetch), Wih+Whh frags in regs,
//                    h dbuf in 8KB LDS (1 barrier/step). LDS 9.25KB ->
//                    4 blocks/CU co-resident.
//   3) gemm_out    : y = agg@Wl.T + bl + x@Wr.T (+res)(+relu), dual fp32+bf16

#define N_NODES 20000
#define DEG 16

typedef __bf16 bf16x8 __attribute__((ext_vector_type(8)));
typedef float f32x4 __attribute__((ext_vector_type(4)));

__device__ inline unsigned short f2bf(float f) {
  unsigned u = __builtin_bit_cast(unsigned, f);
  u += 0x7fffu + ((u >> 16) & 1u);
  return (unsigned short)(u >> 16);
}
__device__ inline float fexp2(float x) {
#if __has_builtin(__builtin_amdgcn_exp2f)
  return __builtin_amdgcn_exp2f(x);
#else
  return exp2f(x);
#endif
}
__device__ inline float frcp(float x) {
#if __has_builtin(__builtin_amdgcn_rcpf)
  return __builtin_amdgcn_rcpf(x);
#else
  return 1.f / x;
#endif
}
__device__ inline float sigm(float x) { return frcp(1.f + fexp2(-1.44269504f * x)); }
__device__ inline float tanh_(float x) { return frcp(1.f + fexp2(-2.88539008f * x)) * 2.f - 1.f; }

// ---------------------------------------------------------------------------
// prep: weights fp32 -> bf16 (all 4 layers), bsum = bih + bhh
// ---------------------------------------------------------------------------
__global__ __launch_bounds__(256) void prep_weights(
    const float* __restrict__ Wih, const float* __restrict__ Whh,
    const float* __restrict__ bih, const float* __restrict__ bhh,
    unsigned short* __restrict__ WihB, unsigned short* __restrict__ WhhB,
    float* __restrict__ bsum) {
  int tid = blockIdx.x * 256 + threadIdx.x;  // 0..65535
  float4 a = *(const float4*)(Wih + tid * 4);
  ushort4 o;
  o.x = f2bf(a.x); o.y = f2bf(a.y); o.z = f2bf(a.z); o.w = f2bf(a.w);
  *(ushort4*)(WihB + tid * 4) = o;
  float4 b = *(const float4*)(Whh + tid * 4);
  ushort4 p;
  p.x = f2bf(b.x); p.y = f2bf(b.y); p.z = f2bf(b.z); p.w = f2bf(b.w);
  *(ushort4*)(WhhB + tid * 4) = p;
  if (tid < 2048) bsum[tid] = bih[tid] + bhh[tid];
}

// ---------------------------------------------------------------------------
// cast: xbf = bf16(x)
// ---------------------------------------------------------------------------
__global__ __launch_bounds__(256) void cast_bf(
    const float* __restrict__ x, unsigned short* __restrict__ xb) {
  int tid = blockIdx.x * 256 + threadIdx.x;
  float4 v = *(const float4*)(x + tid * 4);
  ushort4 o;
  o.x = f2bf(v.x); o.y = f2bf(v.y); o.z = f2bf(v.z); o.w = f2bf(v.w);
  *(ushort4*)(xb + tid * 4) = o;
}

// ---------------------------------------------------------------------------
// lstm_fused: WG = 16 nodes, 8 waves; wave w owns gate-cols {g*128 + w*16+l15}.
// Per step: x A-frags gathered straight from global (lane(l15,l4) reads 16B of
// row idx[t*16+l15] at byte kt*64+l4*16 — exactly the fragment layout),
// prefetched one step ahead; gates = bias + x@Wih.T + h@Whh.T (MFMA);
// activations lane-local; h through 2x4KB LDS dbuf, 1 barrier/step.
// ---------------------------------------------------------------------------
__global__ __launch_bounds__(512) void lstm_fused(
    const unsigned short* __restrict__ xbf,   // [N][128] bf16
    const int* __restrict__ src,              // [E]
    const unsigned short* __restrict__ WihB,  // [512][128] bf16 (layer slice)
    const unsigned short* __restrict__ WhhB,  // [512][128] bf16
    const float* __restrict__ bsum,           // [512]
    float* __restrict__ agg) {                // [N,128] fp32
  __shared__ __align__(16) unsigned char hbuf[2][16 * 256];  // 8KB h double-buffer
  __shared__ __align__(16) int idx_s[256];                   // idx_s[t*16 + node]
  const int tid = threadIdx.x;
  const int lane = tid & 63, w = tid >> 6;
  const int l15 = lane & 15, l4 = lane >> 4;
  const int node0 = blockIdx.x * 16;
  const int colb = w * 16 + l15;  // this wave-lane's output column (per gate)

  // edge indices, transposed to [t][node]
  if (tid < 256) idx_s[(tid & 15) * 16 + (tid >> 4)] = src[node0 * DEG + tid];

  // weight B-fragments (bf16): B[k][n] = W[gate*128+colb][k]
  bf16x8 bwx[4][4], bwh[4][4];
  float bs[4];
#pragma unroll
  for (int g = 0; g < 4; ++g) {
#pragma unroll
    for (int kt = 0; kt < 4; ++kt) {
      bwx[g][kt] = *(const bf16x8*)(WihB + (g * 128 + colb) * 128 + kt * 32 + l4 * 8);
      bwh[g][kt] = *(const bf16x8*)(WhhB + (g * 128 + colb) * 128 + kt * 32 + l4 * 8);
    }
    bs[g] = bsum[g * 128 + colb];
  }
  __syncthreads();  // idx_s visible

  float c[4] = {0.f, 0.f, 0.f, 0.f};

  // x A-fragment gather: lane (l15 -> node, l4 -> k-chunk) reads 16B x 4
#define LOADX(T, DST)                                                  \
  {                                                                    \
    int idx = idx_s[(T) * 16 + l15];                                   \
    const unsigned short* rp = xbf + idx * 128 + l4 * 8;               \
    DST[0] = *(const bf16x8*)(rp);                                     \
    DST[1] = *(const bf16x8*)(rp + 32);                                \
    DST[2] = *(const bf16x8*)(rp + 64);                                \
    DST[3] = *(const bf16x8*)(rp + 96);                                \
  }

  bf16x8 xc[4], xn[4];
  LOADX(0, xc)

#pragma unroll
  for (int t = 0; t < 16; ++t) {
    if (t < 15) LOADX(t + 1, xn)

    f32x4 acc[4];
#pragma unroll
    for (int g = 0; g < 4; ++g) acc[g] = (f32x4){bs[g], bs[g], bs[g], bs[g]};

    // x-part
#pragma unroll
    for (int g = 0; g < 4; ++g)
#pragma unroll
      for (int kt = 0; kt < 4; ++kt)
        acc[g] = __builtin_amdgcn_mfma_f32_16x16x32_bf16(xc[kt], bwx[g][kt],
                                                         acc[g], 0, 0, 0);

    // h-part (h == 0 at t==0)
    if (t > 0) {
      const unsigned char* hb = hbuf[(t - 1) & 1];
      bf16x8 afh[4];
#pragma unroll
      for (int kt = 0; kt < 4; ++kt) {
        int byte = (l15 * 256 + kt * 64 + l4 * 16) ^ ((l15 & 7) << 4);
        afh[kt] = *(const bf16x8*)(hb + byte);
      }
#pragma unroll
      for (int g = 0; g < 4; ++g)
#pragma unroll
        for (int kt = 0; kt < 4; ++kt)
          acc[g] = __builtin_amdgcn_mfma_f32_16x16x32_bf16(afh[kt], bwh[g][kt],
                                                           acc[g], 0, 0, 0);
    }

    // gates + state update (lane-local; gate tiles share C/D lane mapping)
    float hn[4];
#pragma unroll
    for (int r = 0; r < 4; ++r) {
      float ig = sigm(acc[0][r]), fg = sigm(acc[1][r]);
      float gg = tanh_(acc[2][r]), og = sigm(acc[3][r]);
      float cn = fg * c[r] + ig * gg;
      c[r] = cn;
      hn[r] = og * tanh_(cn);
    }

    if (t < 15) {
      unsigned char* hw = hbuf[t & 1];
#pragma unroll
      for (int r = 0; r < 4; ++r) {
        int m = l4 * 4 + r;
        int byte = (m * 256 + colb * 2) ^ ((m & 7) << 4);
        *(__bf16*)(hw + byte) = (__bf16)hn[r];
      }
      __syncthreads();  // h_t visible; also fences next write into other buf
#pragma unroll
      for (int kt = 0; kt < 4; ++kt) xc[kt] = xn[kt];
    } else {
#pragma unroll
      for (int r = 0; r < 4; ++r)
        agg[(node0 + l4 * 4 + r) * 128 + colb] = hn[r];
    }
  }
#undef LOADX
}

// ---------------------------------------------------------------------------
// gemm_out: out[N,NOUT] = agg@Wl.T + bl + x@Wr.T (+resid) (+relu)
// One K=256 GEMM with A = [agg | x], B = [Wl | Wr]. Optionally dual-writes
// bf16 copy (next layer's gather source).
// ---------------------------------------------------------------------------
__global__ __launch_bounds__(256) void gemm_out(
    const float* __restrict__ A1,   // agg [N,128]
    const float* __restrict__ A2,   // x   [N,128]
    const float* __restrict__ Wl, const float* __restrict__ bl,
    const float* __restrict__ Wr,
    const float* __restrict__ resid,    // nullptr or [N,128]
    float* __restrict__ out,
    unsigned short* __restrict__ outbf,  // nullptr or [N,128] bf16
    int NOUT, int do_relu, int Nrows) {
  __shared__ __align__(16) unsigned char As[64 * 512];  // [64 rows][256 bf16], swizzled
  const int tid = threadIdx.x;
  const int lane = tid & 63, w = tid >> 6;
  const int l15 = lane & 15, l4 = lane >> 4;
  const int row0 = blockIdx.x * 64;

#pragma unroll
  for (int i = 0; i < 16; ++i) {
    int flat = i * 1024 + tid * 4;  // 0..16383
    int r = flat >> 8, c = flat & 255;
    int grow = row0 + r;
    float4 v;
    if (grow < Nrows)
      v = (c < 128) ? *(const float4*)(A1 + grow * 128 + c)
                    : *(const float4*)(A2 + grow * 128 + (c - 128));
    else
      v = make_float4(0.f, 0.f, 0.f, 0.f);
    ushort4 b;
    b.x = f2bf(v.x); b.y = f2bf(v.y); b.z = f2bf(v.z); b.w = f2bf(v.w);
    int byte = (r * 512 + c * 2) ^ ((r & 7) << 4);
    *(ushort4*)(As + byte) = b;
  }
  __syncthreads();

  const int colg = blockIdx.y * 64 + w * 16 + l15;
  bf16x8 bw[8];
#pragma unroll
  for (int kt = 0; kt < 8; ++kt) {
    const float* bp = (kt < 4) ? (Wl + colg * 128 + kt * 32 + l4 * 8)
                               : (Wr + colg * 128 + (kt - 4) * 32 + l4 * 8);
    float4 a = *(const float4*)bp;
    float4 b = *(const float4*)(bp + 4);
    bf16x8 v;
    v[0] = (__bf16)a.x; v[1] = (__bf16)a.y; v[2] = (__bf16)a.z; v[3] = (__bf16)a.w;
    v[4] = (__bf16)b.x; v[5] = (__bf16)b.y; v[6] = (__bf16)b.z; v[7] = (__bf16)b.w;
    bw[kt] = v;
  }

  f32x4 acc[4];
#pragma unroll
  for (int rt = 0; rt < 4; ++rt) acc[rt] = (f32x4){0.f, 0.f, 0.f, 0.f};

#pragma unroll
  for (int kt = 0; kt < 8; ++kt) {
#pragma unroll
    for (int rt = 0; rt < 4; ++rt) {
      int m = rt * 16 + l15;
      int byte = (m * 512 + kt * 64 + l4 * 16) ^ ((m & 7) << 4);
      bf16x8 af = *(const bf16x8*)(As + byte);
      acc[rt] = __builtin_amdgcn_mfma_f32_16x16x32_bf16(af, bw[kt], acc[rt], 0, 0, 0);
    }
  }

  const float bias = bl[colg];
#pragma unroll
  for (int rt = 0; rt < 4; ++rt)
#pragma unroll
    for (int r = 0; r < 4; ++r) {
      int grow = row0 + rt * 16 + l4 * 4 + r;
      if (grow < Nrows) {
        float v = acc[rt][r] + bias;
        if (resid) v += resid[grow * 128 + colg];
        if (do_relu) v = fmaxf(v, 0.f);
        out[grow * NOUT + colg] = v;
        if (outbf) outbf[grow * 128 + colg] = f2bf(v);
      }
    }
}

// ---------------------------------------------------------------------------
extern "C" void kernel_launch(void* const* d_in, const int* in_sizes, int n_in,
                              void* d_out, int out_size, void* d_ws, size_t ws_size,
                              hipStream_t stream) {
  const float* X = (const float*)d_in[0];
  const int* src = (const int*)d_in[1];  // edge_index[0] = first E ints
  const float* Wih = (const float*)d_in[2];
  const float* Whh = (const float*)d_in[3];
  const float* bih = (const float*)d_in[4];
  const float* bhh = (const float*)d_in[5];
  const float* Wl123 = (const float*)d_in[6];
  const float* bl123 = (const float*)d_in[7];
  const float* Wr123 = (const float*)d_in[8];
  const float* Wl4 = (const float*)d_in[9];
  const float* bl4 = (const float*)d_in[10];
  const float* Wr4 = (const float*)d_in[11];
  float* out = (float*)d_out;

  char* ws = (char*)d_ws;
  unsigned short* xbf = (unsigned short*)ws;                 // 5.12 MB
  float* agg = (float*)(ws + 5120000);                       // 10.24 MB
  float* xb0 = (float*)(ws + 15360000);                      // 10.24 MB
  float* xb1 = (float*)(ws + 25600000);                      // 10.24 MB
  unsigned short* WihB = (unsigned short*)(ws + 35840000);   // 0.52 MB
  unsigned short* WhhB = (unsigned short*)(ws + 36364288);   // 0.52 MB
  float* bsumW = (float*)(ws + 36888576);                    // 8 KB

  prep_weights<<<dim3(256), 256, 0, stream>>>(Wih, Whh, bih, bhh, WihB, WhhB, bsumW);
  cast_bf<<<dim3(2500), 256, 0, stream>>>(X, xbf);

  const float* xcur = X;
  for (int L = 0; L < 4; ++L) {
    lstm_fused<<<dim3(1250), 512, 0, stream>>>(xbf, src, WihB + L * 65536,
                                               WhhB + L * 65536, bsumW + L * 512, agg);
    if (L < 3) {
      float* nxt = (L & 1) ? xb1 : xb0;
      gemm_out<<<dim3(313, 2), 256, 0, stream>>>(agg, xcur, Wl123 + L * 16384,
                                                 bl123 + L * 128, Wr123 + L * 16384,
                                                 (L >= 1) ? xcur : nullptr, nxt, xbf,
                                                 128, 1, N_NODES);
      xcur = nxt;
    } else {
      gemm_out<<<dim3(313, 1), 256, 0, stream>>>(agg, xcur, Wl4, bl4, Wr4, nullptr, out,
                                                 nullptr, 64, 0, N_NODES);
    }
  }
}

// Round 6
// 549.499 us; speedup vs baseline: 1.2533x; 1.2533x over previous
//
#include <hip/hip_runtime.h>

// ImprovedGraphSAGE: 4x SAGEConv(aggr='lstm') on MI355X.
// N=20000 nodes, DEG=16, F_IN=HID=128, OUT=64, E=320000.
//
// R6 structure (amortize the barrier-locked step):
//   lstm_fused: 32 nodes/block (625 blocks), 8 waves. Per step:
//     - issue next step's 32 x-rows (coalesced 256B row loads, pre-swizzled src)
//     - h-part MFMA from LDS dbuf, x-part MFMA from LDS x dbuf (128 MFMA/step)
//     - activations; ds_write h + staged x; ONE barrier
//   Weights (Wih+Whh bf16 frags) live in registers the whole kernel.

#define N_NODES 20000
#define DEG 16

typedef __bf16 bf16x8 __attribute__((ext_vector_type(8)));
typedef float f32x4 __attribute__((ext_vector_type(4)));

__device__ inline unsigned short f2bf(float f) {
  unsigned u = __builtin_bit_cast(unsigned, f);
  u += 0x7fffu + ((u >> 16) & 1u);
  return (unsigned short)(u >> 16);
}
__device__ inline float fexp2(float x) {
#if __has_builtin(__builtin_amdgcn_exp2f)
  return __builtin_amdgcn_exp2f(x);
#else
  return exp2f(x);
#endif
}
__device__ inline float frcp(float x) {
#if __has_builtin(__builtin_amdgcn_rcpf)
  return __builtin_amdgcn_rcpf(x);
#else
  return 1.f / x;
#endif
}
__device__ inline float sigm(float x) { return frcp(1.f + fexp2(-1.44269504f * x)); }
__device__ inline float tanh_(float x) { return frcp(1.f + fexp2(-2.88539008f * x)) * 2.f - 1.f; }

// ---------------------------------------------------------------------------
// prep: weights fp32 -> bf16 (all 4 layers), bsum = bih + bhh
// ---------------------------------------------------------------------------
__global__ __launch_bounds__(256) void prep_weights(
    const float* __restrict__ Wih, const float* __restrict__ Whh,
    const float* __restrict__ bih, const float* __restrict__ bhh,
    unsigned short* __restrict__ WihB, unsigned short* __restrict__ WhhB,
    float* __restrict__ bsum) {
  int tid = blockIdx.x * 256 + threadIdx.x;  // 0..65535
  float4 a = *(const float4*)(Wih + tid * 4);
  ushort4 o;
  o.x = f2bf(a.x); o.y = f2bf(a.y); o.z = f2bf(a.z); o.w = f2bf(a.w);
  *(ushort4*)(WihB + tid * 4) = o;
  float4 b = *(const float4*)(Whh + tid * 4);
  ushort4 p;
  p.x = f2bf(b.x); p.y = f2bf(b.y); p.z = f2bf(b.z); p.w = f2bf(b.w);
  *(ushort4*)(WhhB + tid * 4) = p;
  if (tid < 2048) bsum[tid] = bih[tid] + bhh[tid];
}

// ---------------------------------------------------------------------------
// cast: xbf = bf16(x)
// ---------------------------------------------------------------------------
__global__ __launch_bounds__(256) void cast_bf(
    const float* __restrict__ x, unsigned short* __restrict__ xb) {
  int tid = blockIdx.x * 256 + threadIdx.x;
  float4 v = *(const float4*)(x + tid * 4);
  ushort4 o;
  o.x = f2bf(v.x); o.y = f2bf(v.y); o.z = f2bf(v.z); o.w = f2bf(v.w);
  *(ushort4*)(xb + tid * 4) = o;
}

// ---------------------------------------------------------------------------
// lstm_fused: WG = 32 nodes, 8 waves; wave w owns gate-cols {g*128 + w*16+l15}.
// Per step t:
//   issue gather of step t+1's 32 x rows (wave w: rows w*4..w*4+3, 16B/lane,
//     global source chunk pre-swizzled so LDS stays linear-write / XOR-read)
//   x-part : 2 row-tiles x 4 gates x 4 kt MFMA from xsb[t&1]
//   h-part : same from hbuf[(t-1)&1]            (skipped at t==0)
//   activations (lane-local), h -> hbuf[t&1], staged x -> xsb[(t+1)&1]
//   ONE __syncthreads per step.
// ---------------------------------------------------------------------------
__global__ __launch_bounds__(512, 2) void lstm_fused(
    const unsigned short* __restrict__ xbf,   // [N][128] bf16
    const int* __restrict__ src,              // [E]
    const unsigned short* __restrict__ WihB,  // [512][128] bf16 (layer slice)
    const unsigned short* __restrict__ WhhB,  // [512][128] bf16
    const float* __restrict__ bsum,           // [512]
    float* __restrict__ agg) {                // [N,128] fp32
  __shared__ __align__(16) unsigned char xsb[2][32 * 256];   // x dbuf (16KB)
  __shared__ __align__(16) unsigned char hbuf[2][32 * 256];  // h dbuf (16KB)
  __shared__ __align__(16) int idx_s[512];                   // idx_s[t*32 + node]
  const int tid = threadIdx.x;
  const int lane = tid & 63, w = tid >> 6;
  const int l15 = lane & 15, l4 = lane >> 4;
  const int node0 = blockIdx.x * 32;
  const int colb = w * 16 + l15;  // this wave-lane's output column (per gate)

  // edge indices, transposed to [t][node]: tid -> (node=tid>>4, t=tid&15)
  idx_s[(tid & 15) * 32 + (tid >> 4)] = src[node0 * DEG + tid];

  // weight B-fragments (bf16): B[k][n] = W[gate*128+colb][k]
  bf16x8 bwx[4][4], bwh[4][4];
  float bs[4];
#pragma unroll
  for (int g = 0; g < 4; ++g) {
#pragma unroll
    for (int kt = 0; kt < 4; ++kt) {
      bwx[g][kt] = *(const bf16x8*)(WihB + (g * 128 + colb) * 128 + kt * 32 + l4 * 8);
      bwh[g][kt] = *(const bf16x8*)(WhhB + (g * 128 + colb) * 128 + kt * 32 + l4 * 8);
    }
    bs[g] = bsum[g * 128 + colb];
  }
  __syncthreads();  // idx_s visible

  // staging geometry: wave w stages rows erow = w*4 + l4, 16B chunk per lane.
  // LDS physical chunk s holds logical chunk s ^ (erow&7)  (matches XOR read).
  const int erow = w * 4 + l4;                 // 0..31
  const int schunk = l15 ^ (erow & 7);         // pre-swizzled global chunk

  // prologue: stage x rows for t=0
  {
    int idx = idx_s[erow];  // t=0
    uint4 v = *(const uint4*)(xbf + idx * 128 + schunk * 8);
    *(uint4*)(&xsb[0][erow * 256 + l15 * 16]) = v;
  }
  __syncthreads();  // xsb[0] ready

  float c[2][4] = {{0.f, 0.f, 0.f, 0.f}, {0.f, 0.f, 0.f, 0.f}};

  for (int t = 0; t < 16; ++t) {
    // (a) issue next step's x gather into regs (consumed by ds_write at step end)
    uint4 xstg;
    if (t < 15) {
      int idx = idx_s[(t + 1) * 32 + erow];
      xstg = *(const uint4*)(xbf + idx * 128 + schunk * 8);
    }

    const unsigned char* xrb = xsb[t & 1];
    f32x4 acc[2][4];
#pragma unroll
    for (int rt = 0; rt < 2; ++rt)
#pragma unroll
      for (int g = 0; g < 4; ++g) acc[rt][g] = (f32x4){bs[g], bs[g], bs[g], bs[g]};

    // x-part: A rows = staged rows m = rt*16 + l15
#pragma unroll
    for (int rt = 0; rt < 2; ++rt) {
      bf16x8 afx[4];
#pragma unroll
      for (int kt = 0; kt < 4; ++kt) {
        int m = rt * 16 + l15;
        int byte = (m * 256 + kt * 64 + l4 * 16) ^ ((m & 7) << 4);
        afx[kt] = *(const bf16x8*)(xrb + byte);
      }
#pragma unroll
      for (int g = 0; g < 4; ++g)
#pragma unroll
        for (int kt = 0; kt < 4; ++kt)
          acc[rt][g] = __builtin_amdgcn_mfma_f32_16x16x32_bf16(afx[kt], bwx[g][kt],
                                                               acc[rt][g], 0, 0, 0);
    }

    // h-part (h == 0 at t==0)
    if (t > 0) {
      const unsigned char* hb = hbuf[(t - 1) & 1];
#pragma unroll
      for (int rt = 0; rt < 2; ++rt) {
        bf16x8 afh[4];
#pragma unroll
        for (int kt = 0; kt < 4; ++kt) {
          int m = rt * 16 + l15;
          int byte = (m * 256 + kt * 64 + l4 * 16) ^ ((m & 7) << 4);
          afh[kt] = *(const bf16x8*)(hb + byte);
        }
#pragma unroll
        for (int g = 0; g < 4; ++g)
#pragma unroll
          for (int kt = 0; kt < 4; ++kt)
            acc[rt][g] = __builtin_amdgcn_mfma_f32_16x16x32_bf16(afh[kt], bwh[g][kt],
                                                                 acc[rt][g], 0, 0, 0);
      }
    }

    // gates + state update (lane-local; gate tiles share C/D lane mapping)
    float hn[2][4];
#pragma unroll
    for (int rt = 0; rt < 2; ++rt)
#pragma unroll
      for (int r = 0; r < 4; ++r) {
        float ig = sigm(acc[rt][0][r]), fg = sigm(acc[rt][1][r]);
        float gg = tanh_(acc[rt][2][r]), og = sigm(acc[rt][3][r]);
        float cn = fg * c[rt][r] + ig * gg;
        c[rt][r] = cn;
        hn[rt][r] = og * tanh_(cn);
      }

    if (t < 15) {
      // write h_t (swizzled)
      unsigned char* hw = hbuf[t & 1];
#pragma unroll
      for (int rt = 0; rt < 2; ++rt)
#pragma unroll
        for (int r = 0; r < 4; ++r) {
          int m = rt * 16 + l4 * 4 + r;
          int byte = (m * 256 + colb * 2) ^ ((m & 7) << 4);
          *(__bf16*)(hw + byte) = (__bf16)hn[rt][r];
        }
      // write staged x for t+1 (linear; src was pre-swizzled)
      *(uint4*)(&xsb[(t + 1) & 1][erow * 256 + l15 * 16]) = xstg;
      __syncthreads();  // h_t and x_{t+1} visible to all
    } else {
#pragma unroll
      for (int rt = 0; rt < 2; ++rt)
#pragma unroll
        for (int r = 0; r < 4; ++r)
          agg[(node0 + rt * 16 + l4 * 4 + r) * 128 + colb] = hn[rt][r];
    }
  }
}

// ---------------------------------------------------------------------------
// gemm_out: out[N,NOUT] = agg@Wl.T + bl + x@Wr.T (+resid) (+relu)
// One K=256 GEMM with A = [agg | x], B = [Wl | Wr]. Optionally dual-writes
// bf16 copy (next layer's gather source).
// ---------------------------------------------------------------------------
__global__ __launch_bounds__(256) void gemm_out(
    const float* __restrict__ A1,   // agg [N,128]
    const float* __restrict__ A2,   // x   [N,128]
    const float* __restrict__ Wl, const float* __restrict__ bl,
    const float* __restrict__ Wr,
    const float* __restrict__ resid,    // nullptr or [N,128]
    float* __restrict__ out,
    unsigned short* __restrict__ outbf,  // nullptr or [N,128] bf16
    int NOUT, int do_relu, int Nrows) {
  __shared__ __align__(16) unsigned char As[64 * 512];  // [64 rows][256 bf16], swizzled
  const int tid = threadIdx.x;
  const int lane = tid & 63, w = tid >> 6;
  const int l15 = lane & 15, l4 = lane >> 4;
  const int row0 = blockIdx.x * 64;

#pragma unroll
  for (int i = 0; i < 16; ++i) {
    int flat = i * 1024 + tid * 4;  // 0..16383
    int r = flat >> 8, c = flat & 255;
    int grow = row0 + r;
    float4 v;
    if (grow < Nrows)
      v = (c < 128) ? *(const float4*)(A1 + grow * 128 + c)
                    : *(const float4*)(A2 + grow * 128 + (c - 128));
    else
      v = make_float4(0.f, 0.f, 0.f, 0.f);
    ushort4 b;
    b.x = f2bf(v.x); b.y = f2bf(v.y); b.z = f2bf(v.z); b.w = f2bf(v.w);
    int byte = (r * 512 + c * 2) ^ ((r & 7) << 4);
    *(ushort4*)(As + byte) = b;
  }
  __syncthreads();

  const int colg = blockIdx.y * 64 + w * 16 + l15;
  bf16x8 bw[8];
#pragma unroll
  for (int kt = 0; kt < 8; ++kt) {
    const float* bp = (kt < 4) ? (Wl + colg * 128 + kt * 32 + l4 * 8)
                               : (Wr + colg * 128 + (kt - 4) * 32 + l4 * 8);
    float4 a = *(const float4*)bp;
    float4 b = *(const float4*)(bp + 4);
    bf16x8 v;
    v[0] = (__bf16)a.x; v[1] = (__bf16)a.y; v[2] = (__bf16)a.z; v[3] = (__bf16)a.w;
    v[4] = (__bf16)b.x; v[5] = (__bf16)b.y; v[6] = (__bf16)b.z; v[7] = (__bf16)b.w;
    bw[kt] = v;
  }

  f32x4 acc[4];
#pragma unroll
  for (int rt = 0; rt < 4; ++rt) acc[rt] = (f32x4){0.f, 0.f, 0.f, 0.f};

#pragma unroll
  for (int kt = 0; kt < 8; ++kt) {
#pragma unroll
    for (int rt = 0; rt < 4; ++rt) {
      int m = rt * 16 + l15;
      int byte = (m * 512 + kt * 64 + l4 * 16) ^ ((m & 7) << 4);
      bf16x8 af = *(const bf16x8*)(As + byte);
      acc[rt] = __builtin_amdgcn_mfma_f32_16x16x32_bf16(af, bw[kt], acc[rt], 0, 0, 0);
    }
  }

  const float bias = bl[colg];
#pragma unroll
  for (int rt = 0; rt < 4; ++rt)
#pragma unroll
    for (int r = 0; r < 4; ++r) {
      int grow = row0 + rt * 16 + l4 * 4 + r;
      if (grow < Nrows) {
        float v = acc[rt][r] + bias;
        if (resid) v += resid[grow * 128 + colg];
        if (do_relu) v = fmaxf(v, 0.f);
        out[grow * NOUT + colg] = v;
        if (outbf) outbf[grow * 128 + colg] = f2bf(v);
      }
    }
}

// ---------------------------------------------------------------------------
extern "C" void kernel_launch(void* const* d_in, const int* in_sizes, int n_in,
                              void* d_out, int out_size, void* d_ws, size_t ws_size,
                              hipStream_t stream) {
  const float* X = (const float*)d_in[0];
  const int* src = (const int*)d_in[1];  // edge_index[0] = first E ints
  const float* Wih = (const float*)d_in[2];
  const float* Whh = (const float*)d_in[3];
  const float* bih = (const float*)d_in[4];
  const float* bhh = (const float*)d_in[5];
  const float* Wl123 = (const float*)d_in[6];
  const float* bl123 = (const float*)d_in[7];
  const float* Wr123 = (const float*)d_in[8];
  const float* Wl4 = (const float*)d_in[9];
  const float* bl4 = (const float*)d_in[10];
  const float* Wr4 = (const float*)d_in[11];
  float* out = (float*)d_out;

  char* ws = (char*)d_ws;
  unsigned short* xbf = (unsigned short*)ws;                 // 5.12 MB
  float* agg = (float*)(ws + 5120000);                       // 10.24 MB
  float* xb0 = (float*)(ws + 15360000);                      // 10.24 MB
  float* xb1 = (float*)(ws + 25600000);                      // 10.24 MB
  unsigned short* WihB = (unsigned short*)(ws + 35840000);   // 0.52 MB
  unsigned short* WhhB = (unsigned short*)(ws + 36364288);   // 0.52 MB
  float* bsumW = (float*)(ws + 36888576);                    // 8 KB

  prep_weights<<<dim3(256), 256, 0, stream>>>(Wih, Whh, bih, bhh, WihB, WhhB, bsumW);
  cast_bf<<<dim3(2500), 256, 0, stream>>>(X, xbf);

  const float* xcur = X;
  for (int L = 0; L < 4; ++L) {
    lstm_fused<<<dim3(625), 512, 0, stream>>>(xbf, src, WihB + L * 65536,
                                              WhhB + L * 65536, bsumW + L * 512, agg);
    if (L < 3) {
      float* nxt = (L & 1) ? xb1 : xb0;
      gemm_out<<<dim3(313, 2), 256, 0, stream>>>(agg, xcur, Wl123 + L * 16384,
                                                 bl123 + L * 128, Wr123 + L * 16384,
                                                 (L >= 1) ? xcur : nullptr, nxt, xbf,
                                                 128, 1, N_NODES);
      xcur = nxt;
    } else {
      gemm_out<<<dim3(313, 1), 256, 0, stream>>>(agg, xcur, Wl4, bl4, Wr4, nullptr, out,
                                                 nullptr, 64, 0, N_NODES);
    }
  }
}

// Round 7
// 546.019 us; speedup vs baseline: 1.2613x; 1.0064x over previous
//
#include <hip/hip_runtime.h>

// ImprovedGraphSAGE: 4x SAGEConv(aggr='lstm') on MI355X.
// N=20000 nodes, DEG=16, F_IN=HID=128, OUT=64, E=320000.
//
// R7 = R6 + counted-wait barriers in lstm_fused:
//   __syncthreads() (drains vmcnt(0) every step -> kills prefetch) is replaced
//   by "s_waitcnt lgkmcnt(0); s_barrier" so the staged-x global loads stay in
//   flight across step barriers (AITER/T4 pattern); their completion is
//   enforced by the compiler's counted vmcnt wait at the ds_write that
//   consumes them.

#define N_NODES 20000
#define DEG 16

typedef __bf16 bf16x8 __attribute__((ext_vector_type(8)));
typedef float f32x4 __attribute__((ext_vector_type(4)));

__device__ inline unsigned short f2bf(float f) {
  unsigned u = __builtin_bit_cast(unsigned, f);
  u += 0x7fffu + ((u >> 16) & 1u);
  return (unsigned short)(u >> 16);
}
__device__ inline float fexp2(float x) {
#if __has_builtin(__builtin_amdgcn_exp2f)
  return __builtin_amdgcn_exp2f(x);
#else
  return exp2f(x);
#endif
}
__device__ inline float frcp(float x) {
#if __has_builtin(__builtin_amdgcn_rcpf)
  return __builtin_amdgcn_rcpf(x);
#else
  return 1.f / x;
#endif
}
__device__ inline float sigm(float x) { return frcp(1.f + fexp2(-1.44269504f * x)); }
__device__ inline float tanh_(float x) { return frcp(1.f + fexp2(-2.88539008f * x)) * 2.f - 1.f; }

// LDS-only barrier: flush LDS ops, sync execution, but leave global loads
// in flight (no vmcnt drain). Their consumers get compiler-counted waits.
__device__ inline void barrier_lds() {
  asm volatile("s_waitcnt lgkmcnt(0)\n\ts_barrier" ::: "memory");
}

// ---------------------------------------------------------------------------
// prep: weights fp32 -> bf16 (all 4 layers), bsum = bih + bhh
// ---------------------------------------------------------------------------
__global__ __launch_bounds__(256) void prep_weights(
    const float* __restrict__ Wih, const float* __restrict__ Whh,
    const float* __restrict__ bih, const float* __restrict__ bhh,
    unsigned short* __restrict__ WihB, unsigned short* __restrict__ WhhB,
    float* __restrict__ bsum) {
  int tid = blockIdx.x * 256 + threadIdx.x;  // 0..65535
  float4 a = *(const float4*)(Wih + tid * 4);
  ushort4 o;
  o.x = f2bf(a.x); o.y = f2bf(a.y); o.z = f2bf(a.z); o.w = f2bf(a.w);
  *(ushort4*)(WihB + tid * 4) = o;
  float4 b = *(const float4*)(Whh + tid * 4);
  ushort4 p;
  p.x = f2bf(b.x); p.y = f2bf(b.y); p.z = f2bf(b.z); p.w = f2bf(b.w);
  *(ushort4*)(WhhB + tid * 4) = p;
  if (tid < 2048) bsum[tid] = bih[tid] + bhh[tid];
}

// ---------------------------------------------------------------------------
// cast: xbf = bf16(x)
// ---------------------------------------------------------------------------
__global__ __launch_bounds__(256) void cast_bf(
    const float* __restrict__ x, unsigned short* __restrict__ xb) {
  int tid = blockIdx.x * 256 + threadIdx.x;
  float4 v = *(const float4*)(x + tid * 4);
  ushort4 o;
  o.x = f2bf(v.x); o.y = f2bf(v.y); o.z = f2bf(v.z); o.w = f2bf(v.w);
  *(ushort4*)(xb + tid * 4) = o;
}

// ---------------------------------------------------------------------------
// lstm_fused: WG = 32 nodes, 8 waves; wave w owns gate-cols {g*128 + w*16+l15}.
// Per step t:
//   issue gather of step t+1's 32 x rows (coalesced 256B rows, pre-swizzled)
//   x-part : 2 row-tiles x 4 gates x 4 kt MFMA from xsb[t&1]
//   h-part : same from hbuf[(t-1)&1]            (skipped at t==0)
//   activations (lane-local), h -> hbuf[t&1], staged x -> xsb[(t+1)&1]
//   ONE lgkmcnt-only barrier per step (global loads float across it).
// ---------------------------------------------------------------------------
__global__ __launch_bounds__(512, 2) void lstm_fused(
    const unsigned short* __restrict__ xbf,   // [N][128] bf16
    const int* __restrict__ src,              // [E]
    const unsigned short* __restrict__ WihB,  // [512][128] bf16 (layer slice)
    const unsigned short* __restrict__ WhhB,  // [512][128] bf16
    const float* __restrict__ bsum,           // [512]
    float* __restrict__ agg) {                // [N,128] fp32
  __shared__ __align__(16) unsigned char xsb[2][32 * 256];   // x dbuf (16KB)
  __shared__ __align__(16) unsigned char hbuf[2][32 * 256];  // h dbuf (16KB)
  __shared__ __align__(16) int idx_s[512];                   // idx_s[t*32 + node]
  const int tid = threadIdx.x;
  const int lane = tid & 63, w = tid >> 6;
  const int l15 = lane & 15, l4 = lane >> 4;
  const int node0 = blockIdx.x * 32;
  const int colb = w * 16 + l15;  // this wave-lane's output column (per gate)

  // edge indices, transposed to [t][node]: tid -> (node=tid>>4, t=tid&15)
  idx_s[(tid & 15) * 32 + (tid >> 4)] = src[node0 * DEG + tid];

  // weight B-fragments (bf16): B[k][n] = W[gate*128+colb][k]
  bf16x8 bwx[4][4], bwh[4][4];
  float bs[4];
#pragma unroll
  for (int g = 0; g < 4; ++g) {
#pragma unroll
    for (int kt = 0; kt < 4; ++kt) {
      bwx[g][kt] = *(const bf16x8*)(WihB + (g * 128 + colb) * 128 + kt * 32 + l4 * 8);
      bwh[g][kt] = *(const bf16x8*)(WhhB + (g * 128 + colb) * 128 + kt * 32 + l4 * 8);
    }
    bs[g] = bsum[g * 128 + colb];
  }
  barrier_lds();  // idx_s visible

  // staging geometry: wave w stages rows erow = w*4 + l4, 16B chunk per lane.
  // LDS physical chunk s holds logical chunk s ^ (erow&7)  (matches XOR read).
  const int erow = w * 4 + l4;                 // 0..31
  const int schunk = l15 ^ (erow & 7);         // pre-swizzled global chunk

  // prologue: stage x rows for t=0
  {
    int idx = idx_s[erow];  // t=0
    uint4 v = *(const uint4*)(xbf + idx * 128 + schunk * 8);
    *(uint4*)(&xsb[0][erow * 256 + l15 * 16]) = v;
  }
  barrier_lds();  // xsb[0] ready

  float c[2][4] = {{0.f, 0.f, 0.f, 0.f}, {0.f, 0.f, 0.f, 0.f}};

  for (int t = 0; t < 16; ++t) {
    // (a) issue next step's x gather into regs (consumed by ds_write at step
    // end; the load stays in flight across intervening code — barriers do not
    // drain vmcnt).
    uint4 xstg;
    if (t < 15) {
      int idx = idx_s[(t + 1) * 32 + erow];
      xstg = *(const uint4*)(xbf + idx * 128 + schunk * 8);
    }

    const unsigned char* xrb = xsb[t & 1];
    f32x4 acc[2][4];
#pragma unroll
    for (int rt = 0; rt < 2; ++rt)
#pragma unroll
      for (int g = 0; g < 4; ++g) acc[rt][g] = (f32x4){bs[g], bs[g], bs[g], bs[g]};

    // x-part: A rows = staged rows m = rt*16 + l15
#pragma unroll
    for (int rt = 0; rt < 2; ++rt) {
      bf16x8 afx[4];
#pragma unroll
      for (int kt = 0; kt < 4; ++kt) {
        int m = rt * 16 + l15;
        int byte = (m * 256 + kt * 64 + l4 * 16) ^ ((m & 7) << 4);
        afx[kt] = *(const bf16x8*)(xrb + byte);
      }
#pragma unroll
      for (int g = 0; g < 4; ++g)
#pragma unroll
        for (int kt = 0; kt < 4; ++kt)
          acc[rt][g] = __builtin_amdgcn_mfma_f32_16x16x32_bf16(afx[kt], bwx[g][kt],
                                                               acc[rt][g], 0, 0, 0);
    }

    // h-part (h == 0 at t==0)
    if (t > 0) {
      const unsigned char* hb = hbuf[(t - 1) & 1];
#pragma unroll
      for (int rt = 0; rt < 2; ++rt) {
        bf16x8 afh[4];
#pragma unroll
        for (int kt = 0; kt < 4; ++kt) {
          int m = rt * 16 + l15;
          int byte = (m * 256 + kt * 64 + l4 * 16) ^ ((m & 7) << 4);
          afh[kt] = *(const bf16x8*)(hb + byte);
        }
#pragma unroll
        for (int g = 0; g < 4; ++g)
#pragma unroll
          for (int kt = 0; kt < 4; ++kt)
            acc[rt][g] = __builtin_amdgcn_mfma_f32_16x16x32_bf16(afh[kt], bwh[g][kt],
                                                                 acc[rt][g], 0, 0, 0);
      }
    }

    // gates + state update (lane-local; gate tiles share C/D lane mapping)
    float hn[2][4];
#pragma unroll
    for (int rt = 0; rt < 2; ++rt)
#pragma unroll
      for (int r = 0; r < 4; ++r) {
        float ig = sigm(acc[rt][0][r]), fg = sigm(acc[rt][1][r]);
        float gg = tanh_(acc[rt][2][r]), og = sigm(acc[rt][3][r]);
        float cn = fg * c[rt][r] + ig * gg;
        c[rt][r] = cn;
        hn[rt][r] = og * tanh_(cn);
      }

    if (t < 15) {
      // write h_t (swizzled)
      unsigned char* hw = hbuf[t & 1];
#pragma unroll
      for (int rt = 0; rt < 2; ++rt)
#pragma unroll
        for (int r = 0; r < 4; ++r) {
          int m = rt * 16 + l4 * 4 + r;
          int byte = (m * 256 + colb * 2) ^ ((m & 7) << 4);
          *(__bf16*)(hw + byte) = (__bf16)hn[rt][r];
        }
      // write staged x for t+1 (linear; src was pre-swizzled). The compiler
      // inserts a counted vmcnt wait for xstg right here — not vmcnt(0).
      *(uint4*)(&xsb[(t + 1) & 1][erow * 256 + l15 * 16]) = xstg;
      barrier_lds();  // h_t and x_{t+1} visible; loads for t+2 keep flying
    } else {
#pragma unroll
      for (int rt = 0; rt < 2; ++rt)
#pragma unroll
        for (int r = 0; r < 4; ++r)
          agg[(node0 + rt * 16 + l4 * 4 + r) * 128 + colb] = hn[rt][r];
    }
  }
}

// ---------------------------------------------------------------------------
// gemm_out: out[N,NOUT] = agg@Wl.T + bl + x@Wr.T (+resid) (+relu)
// One K=256 GEMM with A = [agg | x], B = [Wl | Wr]. Optionally dual-writes
// bf16 copy (next layer's gather source).
// ---------------------------------------------------------------------------
__global__ __launch_bounds__(256) void gemm_out(
    const float* __restrict__ A1,   // agg [N,128]
    const float* __restrict__ A2,   // x   [N,128]
    const float* __restrict__ Wl, const float* __restrict__ bl,
    const float* __restrict__ Wr,
    const float* __restrict__ resid,    // nullptr or [N,128]
    float* __restrict__ out,
    unsigned short* __restrict__ outbf,  // nullptr or [N,128] bf16
    int NOUT, int do_relu, int Nrows) {
  __shared__ __align__(16) unsigned char As[64 * 512];  // [64 rows][256 bf16], swizzled
  const int tid = threadIdx.x;
  const int lane = tid & 63, w = tid >> 6;
  const int l15 = lane & 15, l4 = lane >> 4;
  const int row0 = blockIdx.x * 64;

#pragma unroll
  for (int i = 0; i < 16; ++i) {
    int flat = i * 1024 + tid * 4;  // 0..16383
    int r = flat >> 8, c = flat & 255;
    int grow = row0 + r;
    float4 v;
    if (grow < Nrows)
      v = (c < 128) ? *(const float4*)(A1 + grow * 128 + c)
                    : *(const float4*)(A2 + grow * 128 + (c - 128));
    else
      v = make_float4(0.f, 0.f, 0.f, 0.f);
    ushort4 b;
    b.x = f2bf(v.x); b.y = f2bf(v.y); b.z = f2bf(v.z); b.w = f2bf(v.w);
    int byte = (r * 512 + c * 2) ^ ((r & 7) << 4);
    *(ushort4*)(As + byte) = b;
  }
  __syncthreads();

  const int colg = blockIdx.y * 64 + w * 16 + l15;
  bf16x8 bw[8];
#pragma unroll
  for (int kt = 0; kt < 8; ++kt) {
    const float* bp = (kt < 4) ? (Wl + colg * 128 + kt * 32 + l4 * 8)
                               : (Wr + colg * 128 + (kt - 4) * 32 + l4 * 8);
    float4 a = *(const float4*)bp;
    float4 b = *(const float4*)(bp + 4);
    bf16x8 v;
    v[0] = (__bf16)a.x; v[1] = (__bf16)a.y; v[2] = (__bf16)a.z; v[3] = (__bf16)a.w;
    v[4] = (__bf16)b.x; v[5] = (__bf16)b.y; v[6] = (__bf16)b.z; v[7] = (__bf16)b.w;
    bw[kt] = v;
  }

  f32x4 acc[4];
#pragma unroll
  for (int rt = 0; rt < 4; ++rt) acc[rt] = (f32x4){0.f, 0.f, 0.f, 0.f};

#pragma unroll
  for (int kt = 0; kt < 8; ++kt) {
#pragma unroll
    for (int rt = 0; rt < 4; ++rt) {
      int m = rt * 16 + l15;
      int byte = (m * 512 + kt * 64 + l4 * 16) ^ ((m & 7) << 4);
      bf16x8 af = *(const bf16x8*)(As + byte);
      acc[rt] = __builtin_amdgcn_mfma_f32_16x16x32_bf16(af, bw[kt], acc[rt], 0, 0, 0);
    }
  }

  const float bias = bl[colg];
#pragma unroll
  for (int rt = 0; rt < 4; ++rt)
#pragma unroll
    for (int r = 0; r < 4; ++r) {
      int grow = row0 + rt * 16 + l4 * 4 + r;
      if (grow < Nrows) {
        float v = acc[rt][r] + bias;
        if (resid) v += resid[grow * 128 + colg];
        if (do_relu) v = fmaxf(v, 0.f);
        out[grow * NOUT + colg] = v;
        if (outbf) outbf[grow * 128 + colg] = f2bf(v);
      }
    }
}

// ---------------------------------------------------------------------------
extern "C" void kernel_launch(void* const* d_in, const int* in_sizes, int n_in,
                              void* d_out, int out_size, void* d_ws, size_t ws_size,
                              hipStream_t stream) {
  const float* X = (const float*)d_in[0];
  const int* src = (const int*)d_in[1];  // edge_index[0] = first E ints
  const float* Wih = (const float*)d_in[2];
  const float* Whh = (const float*)d_in[3];
  const float* bih = (const float*)d_in[4];
  const float* bhh = (const float*)d_in[5];
  const float* Wl123 = (const float*)d_in[6];
  const float* bl123 = (const float*)d_in[7];
  const float* Wr123 = (const float*)d_in[8];
  const float* Wl4 = (const float*)d_in[9];
  const float* bl4 = (const float*)d_in[10];
  const float* Wr4 = (const float*)d_in[11];
  float* out = (float*)d_out;

  char* ws = (char*)d_ws;
  unsigned short* xbf = (unsigned short*)ws;                 // 5.12 MB
  float* agg = (float*)(ws + 5120000);                       // 10.24 MB
  float* xb0 = (float*)(ws + 15360000);                      // 10.24 MB
  float* xb1 = (float*)(ws + 25600000);                      // 10.24 MB
  unsigned short* WihB = (unsigned short*)(ws + 35840000);   // 0.52 MB
  unsigned short* WhhB = (unsigned short*)(ws + 36364288);   // 0.52 MB
  float* bsumW = (float*)(ws + 36888576);                    // 8 KB

  prep_weights<<<dim3(256), 256, 0, stream>>>(Wih, Whh, bih, bhh, WihB, WhhB, bsumW);
  cast_bf<<<dim3(2500), 256, 0, stream>>>(X, xbf);

  const float* xcur = X;
  for (int L = 0; L < 4; ++L) {
    lstm_fused<<<dim3(625), 512, 0, stream>>>(xbf, src, WihB + L * 65536,
                                              WhhB + L * 65536, bsumW + L * 512, agg);
    if (L < 3) {
      float* nxt = (L & 1) ? xb1 : xb0;
      gemm_out<<<dim3(313, 2), 256, 0, stream>>>(agg, xcur, Wl123 + L * 16384,
                                                 bl123 + L * 128, Wr123 + L * 16384,
                                                 (L >= 1) ? xcur : nullptr, nxt, xbf,
                                                 128, 1, N_NODES);
      xcur = nxt;
    } else {
      gemm_out<<<dim3(313, 1), 256, 0, stream>>>(agg, xcur, Wl4, bl4, Wr4, nullptr, out,
                                                 nullptr, 64, 0, N_NODES);
    }
  }
}

// Round 9
// 467.912 us; speedup vs baseline: 1.4719x; 1.1669x over previous
//
#include <hip/hip_runtime.h>

// ImprovedGraphSAGE: 4x SAGEConv(aggr='lstm') on MI355X.
// N=20000 nodes, DEG=16, F_IN=HID=128, OUT=64, E=320000.
//
// R9 = R8 (250 blocks x 80 nodes, per-rt pipelined step) with the swizzle-read
// bug fixed: XOR must be applied to the FULL byte offset (incl. kt*64), since
// the mask (m&7)<<4 overlaps kt*64 at bit 6 (rule #21: write/read involutions
// must match exactly).

#define N_NODES 20000
#define DEG 16
#define NPB 80   // nodes per block
#define RT 5     // row tiles (16 rows each)

typedef __bf16 bf16x8 __attribute__((ext_vector_type(8)));
typedef float f32x4 __attribute__((ext_vector_type(4)));

__device__ inline unsigned short f2bf(float f) {
  unsigned u = __builtin_bit_cast(unsigned, f);
  u += 0x7fffu + ((u >> 16) & 1u);
  return (unsigned short)(u >> 16);
}
__device__ inline float fexp2(float x) {
#if __has_builtin(__builtin_amdgcn_exp2f)
  return __builtin_amdgcn_exp2f(x);
#else
  return exp2f(x);
#endif
}
__device__ inline float frcp(float x) {
#if __has_builtin(__builtin_amdgcn_rcpf)
  return __builtin_amdgcn_rcpf(x);
#else
  return 1.f / x;
#endif
}
__device__ inline float sigm(float x) { return frcp(1.f + fexp2(-1.44269504f * x)); }
__device__ inline float tanh_(float x) { return frcp(1.f + fexp2(-2.88539008f * x)) * 2.f - 1.f; }

// LDS-only barrier: flush LDS ops, sync execution, leave global loads in
// flight (no vmcnt drain); consumers get compiler-counted vmcnt waits.
__device__ inline void barrier_lds() {
  asm volatile("s_waitcnt lgkmcnt(0)\n\ts_barrier" ::: "memory");
}

// ---------------------------------------------------------------------------
// prep: weights fp32 -> bf16 (all 4 layers), bsum = bih + bhh
// ---------------------------------------------------------------------------
__global__ __launch_bounds__(256) void prep_weights(
    const float* __restrict__ Wih, const float* __restrict__ Whh,
    const float* __restrict__ bih, const float* __restrict__ bhh,
    unsigned short* __restrict__ WihB, unsigned short* __restrict__ WhhB,
    float* __restrict__ bsum) {
  int tid = blockIdx.x * 256 + threadIdx.x;  // 0..65535
  float4 a = *(const float4*)(Wih + tid * 4);
  ushort4 o;
  o.x = f2bf(a.x); o.y = f2bf(a.y); o.z = f2bf(a.z); o.w = f2bf(a.w);
  *(ushort4*)(WihB + tid * 4) = o;
  float4 b = *(const float4*)(Whh + tid * 4);
  ushort4 p;
  p.x = f2bf(b.x); p.y = f2bf(b.y); p.z = f2bf(b.z); p.w = f2bf(b.w);
  *(ushort4*)(WhhB + tid * 4) = p;
  if (tid < 2048) bsum[tid] = bih[tid] + bhh[tid];
}

// ---------------------------------------------------------------------------
// cast: xbf = bf16(x)
// ---------------------------------------------------------------------------
__global__ __launch_bounds__(256) void cast_bf(
    const float* __restrict__ x, unsigned short* __restrict__ xb) {
  int tid = blockIdx.x * 256 + threadIdx.x;
  float4 v = *(const float4*)(x + tid * 4);
  ushort4 o;
  o.x = f2bf(v.x); o.y = f2bf(v.y); o.z = f2bf(v.z); o.w = f2bf(v.w);
  *(ushort4*)(xb + tid * 4) = o;
}

// ---------------------------------------------------------------------------
// lstm_fused: WG = 80 nodes, 8 waves; wave w owns gate-cols {g*128 + w*16+l15}.
// ---------------------------------------------------------------------------
__global__ __launch_bounds__(512, 2) void lstm_fused(
    const unsigned short* __restrict__ xbf,   // [N][128] bf16
    const int* __restrict__ src,              // [E]
    const unsigned short* __restrict__ WihB,  // [512][128] bf16 (layer slice)
    const unsigned short* __restrict__ WhhB,  // [512][128] bf16
    const float* __restrict__ bsum,           // [512]
    float* __restrict__ agg) {                // [N,128] fp32
  __shared__ __align__(16) unsigned char xsb[2][NPB * 256];   // x dbuf (40KB)
  __shared__ __align__(16) unsigned char hbuf[2][NPB * 256];  // h dbuf (40KB)
  __shared__ __align__(16) int idx_s[NPB * DEG];              // [t*80 + node]
  const int tid = threadIdx.x;
  const int lane = tid & 63, w = tid >> 6;
  const int l15 = lane & 15, l4 = lane >> 4;
  const int node0 = blockIdx.x * NPB;
  const int colb = w * 16 + l15;  // this wave-lane's output column (per gate)

  // edge indices: task = node*16 + t  ->  idx_s[t*80 + node]
#pragma unroll
  for (int i = 0; i < 3; ++i) {
    int task = tid + i * 512;
    if (task < NPB * DEG) {
      int node = task >> 4, t = task & 15;
      idx_s[t * NPB + node] = src[node0 * DEG + task];
    }
  }

  // weight B-fragments (bf16): B[k][n] = W[gate*128+colb][k]
  bf16x8 bwx[4][4], bwh[4][4];
  float bs[4];
#pragma unroll
  for (int g = 0; g < 4; ++g) {
#pragma unroll
    for (int kt = 0; kt < 4; ++kt) {
      bwx[g][kt] = *(const bf16x8*)(WihB + (g * 128 + colb) * 128 + kt * 32 + l4 * 8);
      bwh[g][kt] = *(const bf16x8*)(WhhB + (g * 128 + colb) * 128 + kt * 32 + l4 * 8);
    }
    bs[g] = bsum[g * 128 + colb];
  }
  barrier_lds();  // idx_s visible

  // staging tasks: task = row*16 + chunk; LDS physical chunk p holds logical
  // chunk p ^ (row&7)  (matches the XOR-swizzled read below).
  const int task0 = tid, task1 = tid + 512;
  const int row0s = task0 >> 4, ch0 = task0 & 15;
  const int row1s = task1 >> 4, ch1 = task1 & 15;
  const int task2 = tid + 1024;
  const bool p2 = task2 < NPB * 16;
  const int row2s = task2 >> 4, ch2 = task2 & 15;

  // prologue: stage x rows for t=0
  {
    uint4 v0 = *(const uint4*)(xbf + idx_s[row0s] * 128 + (ch0 ^ (row0s & 7)) * 8);
    uint4 v1 = *(const uint4*)(xbf + idx_s[row1s] * 128 + (ch1 ^ (row1s & 7)) * 8);
    *(uint4*)(&xsb[0][row0s * 256 + ch0 * 16]) = v0;
    *(uint4*)(&xsb[0][row1s * 256 + ch1 * 16]) = v1;
    if (p2) {
      uint4 v2 = *(const uint4*)(xbf + idx_s[row2s] * 128 + (ch2 ^ (row2s & 7)) * 8);
      *(uint4*)(&xsb[0][row2s * 256 + ch2 * 16]) = v2;
    }
  }
  barrier_lds();  // xsb[0] ready

  float c[RT][4];
#pragma unroll
  for (int rt = 0; rt < RT; ++rt)
#pragma unroll
    for (int r = 0; r < 4; ++r) c[rt][r] = 0.f;

#pragma unroll 2
  for (int t = 0; t < 16; ++t) {
    // (a) issue next step's x gather into regs (T14: write after compute)
    uint4 xstg0, xstg1, xstg2;
    if (t < 15) {
      const int tb = (t + 1) * NPB;
      xstg0 = *(const uint4*)(xbf + idx_s[tb + row0s] * 128 + (ch0 ^ (row0s & 7)) * 8);
      xstg1 = *(const uint4*)(xbf + idx_s[tb + row1s] * 128 + (ch1 ^ (row1s & 7)) * 8);
      if (p2)
        xstg2 = *(const uint4*)(xbf + idx_s[tb + row2s] * 128 + (ch2 ^ (row2s & 7)) * 8);
    }

    const unsigned char* xrb = xsb[t & 1];
    const unsigned char* hb = hbuf[(t + 1) & 1];  // == (t-1)&1
    unsigned char* hw = hbuf[t & 1];

    // per-rt pipelined body: acc live only within one rt
#pragma unroll
    for (int rt = 0; rt < RT; ++rt) {
      f32x4 acc[4];
#pragma unroll
      for (int g = 0; g < 4; ++g) acc[g] = (f32x4){bs[g], bs[g], bs[g], bs[g]};

      const int m = rt * 16 + l15;
      // x-part (XOR on the FULL offset — mask bits overlap kt*64 at bit 6)
#pragma unroll
      for (int kt = 0; kt < 4; ++kt) {
        int byte = (m * 256 + kt * 64 + l4 * 16) ^ ((m & 7) << 4);
        bf16x8 a = *(const bf16x8*)(xrb + byte);
#pragma unroll
        for (int g = 0; g < 4; ++g)
          acc[g] = __builtin_amdgcn_mfma_f32_16x16x32_bf16(a, bwx[g][kt], acc[g], 0, 0, 0);
      }
      // h-part (h == 0 at t==0)
      if (t > 0) {
#pragma unroll
        for (int kt = 0; kt < 4; ++kt) {
          int byte = (m * 256 + kt * 64 + l4 * 16) ^ ((m & 7) << 4);
          bf16x8 a = *(const bf16x8*)(hb + byte);
#pragma unroll
          for (int g = 0; g < 4; ++g)
            acc[g] = __builtin_amdgcn_mfma_f32_16x16x32_bf16(a, bwh[g][kt], acc[g], 0, 0, 0);
        }
      }

      // gates + state update (lane-local; gate tiles share C/D lane mapping)
#pragma unroll
      for (int r = 0; r < 4; ++r) {
        float ig = sigm(acc[0][r]), fg = sigm(acc[1][r]);
        float gg = tanh_(acc[2][r]), og = sigm(acc[3][r]);
        float cn = fg * c[rt][r] + ig * gg;
        c[rt][r] = cn;
        float hv = og * tanh_(cn);
        int mm = rt * 16 + l4 * 4 + r;
        if (t < 15) {
          int byte = (mm * 256 + colb * 2) ^ ((mm & 7) << 4);
          *(__bf16*)(hw + byte) = (__bf16)hv;
        } else {
          agg[(node0 + mm) * 128 + colb] = hv;
        }
      }
    }

    if (t < 15) {
      // write staged x for t+1 (linear; src was pre-swizzled)
      unsigned char* xw = xsb[(t + 1) & 1];
      *(uint4*)(&xw[row0s * 256 + ch0 * 16]) = xstg0;
      *(uint4*)(&xw[row1s * 256 + ch1 * 16]) = xstg1;
      if (p2) *(uint4*)(&xw[row2s * 256 + ch2 * 16]) = xstg2;
      barrier_lds();  // h_t and x_{t+1} visible; loads keep flying
    }
  }
}

// ---------------------------------------------------------------------------
// gemm_out: out[N,NOUT] = agg@Wl.T + bl + x@Wr.T (+resid) (+relu)
// One K=256 GEMM with A = [agg | x], B = [Wl | Wr]. Optionally dual-writes
// bf16 copy (next layer's gather source).
// ---------------------------------------------------------------------------
__global__ __launch_bounds__(256) void gemm_out(
    const float* __restrict__ A1,   // agg [N,128]
    const float* __restrict__ A2,   // x   [N,128]
    const float* __restrict__ Wl, const float* __restrict__ bl,
    const float* __restrict__ Wr,
    const float* __restrict__ resid,    // nullptr or [N,128]
    float* __restrict__ out,
    unsigned short* __restrict__ outbf,  // nullptr or [N,128] bf16
    int NOUT, int do_relu, int Nrows) {
  __shared__ __align__(16) unsigned char As[64 * 512];  // [64 rows][256 bf16], swizzled
  const int tid = threadIdx.x;
  const int lane = tid & 63, w = tid >> 6;
  const int l15 = lane & 15, l4 = lane >> 4;
  const int row0 = blockIdx.x * 64;

#pragma unroll
  for (int i = 0; i < 16; ++i) {
    int flat = i * 1024 + tid * 4;  // 0..16383
    int r = flat >> 8, c = flat & 255;
    int grow = row0 + r;
    float4 v;
    if (grow < Nrows)
      v = (c < 128) ? *(const float4*)(A1 + grow * 128 + c)
                    : *(const float4*)(A2 + grow * 128 + (c - 128));
    else
      v = make_float4(0.f, 0.f, 0.f, 0.f);
    ushort4 b;
    b.x = f2bf(v.x); b.y = f2bf(v.y); b.z = f2bf(v.z); b.w = f2bf(v.w);
    int byte = (r * 512 + c * 2) ^ ((r & 7) << 4);
    *(ushort4*)(As + byte) = b;
  }
  __syncthreads();

  const int colg = blockIdx.y * 64 + w * 16 + l15;
  bf16x8 bw[8];
#pragma unroll
  for (int kt = 0; kt < 8; ++kt) {
    const float* bp = (kt < 4) ? (Wl + colg * 128 + kt * 32 + l4 * 8)
                               : (Wr + colg * 128 + (kt - 4) * 32 + l4 * 8);
    float4 a = *(const float4*)bp;
    float4 b = *(const float4*)(bp + 4);
    bf16x8 v;
    v[0] = (__bf16)a.x; v[1] = (__bf16)a.y; v[2] = (__bf16)a.z; v[3] = (__bf16)a.w;
    v[4] = (__bf16)b.x; v[5] = (__bf16)b.y; v[6] = (__bf16)b.z; v[7] = (__bf16)b.w;
    bw[kt] = v;
  }

  f32x4 acc[4];
#pragma unroll
  for (int rt = 0; rt < 4; ++rt) acc[rt] = (f32x4){0.f, 0.f, 0.f, 0.f};

#pragma unroll
  for (int kt = 0; kt < 8; ++kt) {
#pragma unroll
    for (int rt = 0; rt < 4; ++rt) {
      int m = rt * 16 + l15;
      int byte = (m * 512 + kt * 64 + l4 * 16) ^ ((m & 7) << 4);
      bf16x8 af = *(const bf16x8*)(As + byte);
      acc[rt] = __builtin_amdgcn_mfma_f32_16x16x32_bf16(af, bw[kt], acc[rt], 0, 0, 0);
    }
  }

  const float bias = bl[colg];
#pragma unroll
  for (int rt = 0; rt < 4; ++rt)
#pragma unroll
    for (int r = 0; r < 4; ++r) {
      int grow = row0 + rt * 16 + l4 * 4 + r;
      if (grow < Nrows) {
        float v = acc[rt][r] + bias;
        if (resid) v += resid[grow * 128 + colg];
        if (do_relu) v = fmaxf(v, 0.f);
        out[grow * NOUT + colg] = v;
        if (outbf) outbf[grow * 128 + colg] = f2bf(v);
      }
    }
}

// ---------------------------------------------------------------------------
extern "C" void kernel_launch(void* const* d_in, const int* in_sizes, int n_in,
                              void* d_out, int out_size, void* d_ws, size_t ws_size,
                              hipStream_t stream) {
  const float* X = (const float*)d_in[0];
  const int* src = (const int*)d_in[1];  // edge_index[0] = first E ints
  const float* Wih = (const float*)d_in[2];
  const float* Whh = (const float*)d_in[3];
  const float* bih = (const float*)d_in[4];
  const float* bhh = (const float*)d_in[5];
  const float* Wl123 = (const float*)d_in[6];
  const float* bl123 = (const float*)d_in[7];
  const float* Wr123 = (const float*)d_in[8];
  const float* Wl4 = (const float*)d_in[9];
  const float* bl4 = (const float*)d_in[10];
  const float* Wr4 = (const float*)d_in[11];
  float* out = (float*)d_out;

  char* ws = (char*)d_ws;
  unsigned short* xbf = (unsigned short*)ws;                 // 5.12 MB
  float* agg = (float*)(ws + 5120000);                       // 10.24 MB
  float* xb0 = (float*)(ws + 15360000);                      // 10.24 MB
  float* xb1 = (float*)(ws + 25600000);                      // 10.24 MB
  unsigned short* WihB = (unsigned short*)(ws + 35840000);   // 0.52 MB
  unsigned short* WhhB = (unsigned short*)(ws + 36364288);   // 0.52 MB
  float* bsumW = (float*)(ws + 36888576);                    // 8 KB

  prep_weights<<<dim3(256), 256, 0, stream>>>(Wih, Whh, bih, bhh, WihB, WhhB, bsumW);
  cast_bf<<<dim3(2500), 256, 0, stream>>>(X, xbf);

  const float* xcur = X;
  for (int L = 0; L < 4; ++L) {
    lstm_fused<<<dim3(250), 512, 0, stream>>>(xbf, src, WihB + L * 65536,
                                              WhhB + L * 65536, bsumW + L * 512, agg);
    if (L < 3) {
      float* nxt = (L & 1) ? xb1 : xb0;
      gemm_out<<<dim3(313, 2), 256, 0, stream>>>(agg, xcur, Wl123 + L * 16384,
                                                 bl123 + L * 128, Wr123 + L * 16384,
                                                 (L >= 1) ? xcur : nullptr, nxt, xbf,
                                                 128, 1, N_NODES);
      xcur = nxt;
    } else {
      gemm_out<<<dim3(313, 1), 256, 0, stream>>>(agg, xcur, Wl4, bl4, Wr4, nullptr, out,
                                                 nullptr, 64, 0, N_NODES);
    }
  }
}